// Round 2
// baseline (782.913 us; speedup 1.0000x reference)
//
#include <hip/hip_runtime.h>
#include <hip/hip_bf16.h>

typedef __attribute__((ext_vector_type(8))) short bf16x8;
typedef __attribute__((ext_vector_type(4))) float f32x4;

#define NROWS  262144
#define MBLK   64
#define NTILES (NROWS / MBLK)    /* 4096 */
#define GRID   512
#define TPB    (NTILES / GRID)   /* 8 tiles per persistent block */

// ---------------------------------------------------------------------------
// Weight prep (unchanged): MFMA B-fragment-layout bf16 hi/lo copies,
// Wbig[gate][n=0..127][k=0..255] (k<128 -> W, else U).
// ---------------------------------------------------------------------------
__global__ void prep_weights(
    const float* __restrict__ Wi, const float* __restrict__ Ui,
    const float* __restrict__ Wf, const float* __restrict__ Uf,
    const float* __restrict__ Wo, const float* __restrict__ Uo,
    const float* __restrict__ Wz, const float* __restrict__ Uz,
    ushort* __restrict__ hi, ushort* __restrict__ lo)
{
    int idx = blockIdx.x * 256 + threadIdx.x;   // 0..131071
    int j    = idx & 7;
    int lane = (idx >> 3) & 63;
    int kk   = (idx >> 9) & 7;
    int ni   = (idx >> 12) & 7;
    int g    = idx >> 15;
    int n = ni * 16 + (lane & 15);
    int k = kk * 32 + (lane >> 4) * 8 + j;
    const float* W; const float* U;
    if (g == 0)      { W = Wi; U = Ui; }
    else if (g == 1) { W = Wf; U = Uf; }
    else if (g == 2) { W = Wo; U = Uo; }
    else             { W = Wz; U = Uz; }
    float w = (k < 128) ? W[n * 128 + k] : U[n * 128 + (k - 128)];
    __hip_bfloat16 hb = __float2bfloat16(w);
    float r = w - __bfloat162float(hb);
    __hip_bfloat16 lb = __float2bfloat16(r);
    hi[idx] = *reinterpret_cast<ushort*>(&hb);
    lo[idx] = *reinterpret_cast<ushort*>(&lb);
}

__device__ inline void cvt_hilo(float v, ushort& h, ushort& l) {
    __hip_bfloat16 hb = __float2bfloat16(v);
    float r = v - __bfloat162float(hb);
    __hip_bfloat16 lb = __float2bfloat16(r);
    h = *reinterpret_cast<ushort*>(&hb);
    l = *reinterpret_cast<ushort*>(&lb);
}

// ---------------------------------------------------------------------------
// Persistent fused kernel. 512 blocks x 8 tiles; block = 512 thr = 8 waves.
// Per tile: writeBF(regs->LDS) | prefetch(t+1 x/h + t c/n into regs) |
// barrier-free K-loop (hides the loads) | swizzled epilogue.
// ---------------------------------------------------------------------------
__global__ __launch_bounds__(512, 2) void slstm_main(
    const float* __restrict__ x,     const float* __restrict__ hprev,
    const float* __restrict__ cprev, const float* __restrict__ nprev,
    const float* __restrict__ bi,    const float* __restrict__ bfg,
    const float* __restrict__ bo,    const float* __restrict__ bz,
    const ushort* __restrict__ whi,  const ushort* __restrict__ wlo,
    float* __restrict__ out)
{
    __shared__ ushort Ahi[64 * 256];   // 32 KB, swizzled bf16-hi of [x|h]
    __shared__ ushort Alo[64 * 256];   // 32 KB, swizzled bf16-lo
    float* pre = reinterpret_cast<float*>(Ahi);   // epilogue alias (32 KB)
    char* AhiB = reinterpret_cast<char*>(Ahi);
    char* AloB = reinterpret_cast<char*>(Alo);

    const int tid  = threadIdx.x;
    const int wid  = tid >> 6;
    const int lane = tid & 63;
    const int g    = wid & 3;          // gate
    const int ch   = wid >> 2;         // column half
    const int l15  = lane & 15;
    const int lg   = lane >> 4;
    const int c    = tid & 127;        // epilogue column
    const int r0   = tid >> 7;         // epilogue row phase
    const float bic = bi[c], bfc = bfg[c], boc = bo[c], bzc = bz[c];
    const size_t OUTS = (size_t)NROWS * 128;

    // ---- prologue: load tile 0's x/h into registers ----
    float4 vx[4], vh[4];
    {
        int row0n = blockIdx.x * MBLK;
        #pragma unroll
        for (int i = 0; i < 4; ++i) {
            int f4 = tid + i * 512, row = f4 >> 5, c4 = f4 & 31;
            vx[i] = reinterpret_cast<const float4*>(x)[(size_t)(row0n + row) * 32 + c4];
            vh[i] = reinterpret_cast<const float4*>(hprev)[(size_t)(row0n + row) * 32 + c4];
        }
    }

    for (int t = 0; t < TPB; ++t) {
        const int row0 = (blockIdx.x + t * GRID) * MBLK;

        __syncthreads();   // prev tile's epilogue LDS reads complete
        // ---- writeBF: regs -> swizzled bf16 hi/lo LDS ----
        #pragma unroll
        for (int i = 0; i < 4; ++i) {
            int f4 = tid + i * 512, row = f4 >> 5, c4 = f4 & 31;
            #pragma unroll
            for (int half = 0; half < 2; ++half) {
                float4 v = half ? vh[i] : vx[i];
                int kbase = half * 128 + 4 * c4;
                int q   = kbase >> 3;
                int sub = (kbase & 7) * 2;
                int byt = row * 512 + ((q ^ (row & 7)) << 4) + sub;
                float vv[4] = {v.x, v.y, v.z, v.w};
                ushort h4[4], l4v[4];
                #pragma unroll
                for (int e = 0; e < 4; ++e) cvt_hilo(vv[e], h4[e], l4v[e]);
                uint2 hp, lp;
                hp.x = (uint)h4[0] | ((uint)h4[1] << 16);
                hp.y = (uint)h4[2] | ((uint)h4[3] << 16);
                lp.x = (uint)l4v[0] | ((uint)l4v[1] << 16);
                lp.y = (uint)l4v[2] | ((uint)l4v[3] << 16);
                *reinterpret_cast<uint2*>(AhiB + byt) = hp;
                *reinterpret_cast<uint2*>(AloB + byt) = lp;
            }
        }
        __syncthreads();

        // ---- prefetch: this tile's c/n + next tile's x/h (hidden under K) ----
        float cpr[4][4], npr[4][4];
        #pragma unroll
        for (int mi = 0; mi < 4; ++mi)
            #pragma unroll
            for (int it = 0; it < 4; ++it) {
                int r = r0 + it * 4;
                size_t gidx = (size_t)(row0 + mi * 16 + r) * 128 + c;
                cpr[mi][it] = cprev[gidx];
                npr[mi][it] = nprev[gidx];
            }
        if (t + 1 < TPB) {
            int row0n = (blockIdx.x + (t + 1) * GRID) * MBLK;
            #pragma unroll
            for (int i = 0; i < 4; ++i) {
                int f4 = tid + i * 512, row = f4 >> 5, c4 = f4 & 31;
                vx[i] = reinterpret_cast<const float4*>(x)[(size_t)(row0n + row) * 32 + c4];
                vh[i] = reinterpret_cast<const float4*>(hprev)[(size_t)(row0n + row) * 32 + c4];
            }
        }

        // ---- K-loop: 3-term split-precision MFMA (barrier-free) ----
        f32x4 acc[4][4] = {};
        #pragma unroll
        for (int kk = 0; kk < 8; ++kk) {
            bf16x8 ah[4], al[4];
            #pragma unroll
            for (int mi = 0; mi < 4; ++mi) {
                int row = mi * 16 + l15;
                int q   = kk * 4 + lg;
                int byt = row * 512 + ((q ^ (row & 7)) << 4);
                ah[mi] = *reinterpret_cast<const bf16x8*>(AhiB + byt);
                al[mi] = *reinterpret_cast<const bf16x8*>(AloB + byt);
            }
            #pragma unroll
            for (int ni = 0; ni < 4; ++ni) {
                int nig = ch * 4 + ni;
                size_t off = (size_t)((((g * 8 + nig) * 8 + kk) * 64) + lane) * 8;
                bf16x8 bh = *reinterpret_cast<const bf16x8*>(whi + off);
                bf16x8 bl = *reinterpret_cast<const bf16x8*>(wlo + off);
                #pragma unroll
                for (int mi = 0; mi < 4; ++mi)
                    acc[mi][ni] = __builtin_amdgcn_mfma_f32_16x16x32_bf16(ah[mi], bh, acc[mi][ni], 0, 0, 0);
                #pragma unroll
                for (int mi = 0; mi < 4; ++mi)
                    acc[mi][ni] = __builtin_amdgcn_mfma_f32_16x16x32_bf16(ah[mi], bl, acc[mi][ni], 0, 0, 0);
                #pragma unroll
                for (int mi = 0; mi < 4; ++mi)
                    acc[mi][ni] = __builtin_amdgcn_mfma_f32_16x16x32_bf16(al[mi], bh, acc[mi][ni], 0, 0, 0);
            }
        }

        // ---- epilogue: 4 chunks of 16 rows via swizzled pre (aliases Ahi) ----
        #pragma unroll
        for (int mi = 0; mi < 4; ++mi) {
            __syncthreads();   // K-loop LDS reads / prev chunk reads done
            #pragma unroll
            for (int ni = 0; ni < 4; ++ni) {
                int colF = g * 128 + ch * 64 + ni * 16 + l15;
                #pragma unroll
                for (int r = 0; r < 4; ++r) {
                    int rowp = lg * 4 + r;
                    pre[rowp * 512 + (colF ^ ((rowp & 4) << 2))] = acc[mi][ni][r];
                }
            }
            __syncthreads();
            #pragma unroll
            for (int it = 0; it < 4; ++it) {
                int r = r0 + it * 4;
                int sw = (r & 4) << 2;
                size_t gidx = (size_t)(row0 + mi * 16 + r) * 128 + c;
                float pit = pre[r * 512 + ((      c) ^ sw)] + bic;
                float pft = pre[r * 512 + ((128 + c) ^ sw)] + bfc;
                float pot = pre[r * 512 + ((256 + c) ^ sw)] + boc;
                float pzt = pre[r * 512 + ((384 + c) ^ sw)] + bzc;
                float m   = fmaxf(pft, pit);
                float i_t = __expf(pit - m);
                float f_t = __builtin_amdgcn_rcpf(1.0f + __expf(-pft)) + __expf(pft - m);
                float o_t = __builtin_amdgcn_rcpf(1.0f + __expf(-pot));
                float zc  = fminf(fmaxf(pzt, -15.0f), 15.0f);
                float e2  = __expf(2.0f * zc);
                float z_t = (e2 - 1.0f) * __builtin_amdgcn_rcpf(e2 + 1.0f);
                float c_t = f_t * cpr[mi][it] + i_t * z_t;
                float n_t = f_t * npr[mi][it] + i_t;
                float h_t = o_t * c_t * __builtin_amdgcn_rcpf(n_t + 1e-8f);
                out[gidx]            = h_t;
                out[OUTS + gidx]     = c_t;
                out[2 * OUTS + gidx] = n_t;
            }
        }
    }
}

extern "C" void kernel_launch(void* const* d_in, const int* in_sizes, int n_in,
                              void* d_out, int out_size, void* d_ws, size_t ws_size,
                              hipStream_t stream) {
    const float* x  = (const float*)d_in[0];
    const float* h  = (const float*)d_in[1];
    const float* cp = (const float*)d_in[2];
    const float* np = (const float*)d_in[3];
    const float* Wi = (const float*)d_in[4];
    const float* Ui = (const float*)d_in[5];
    const float* Wf = (const float*)d_in[6];
    const float* Uf = (const float*)d_in[7];
    const float* Wo = (const float*)d_in[8];
    const float* Uo = (const float*)d_in[9];
    const float* Wz = (const float*)d_in[10];
    const float* Uz = (const float*)d_in[11];
    const float* bi = (const float*)d_in[12];
    const float* bf = (const float*)d_in[13];
    const float* bo = (const float*)d_in[14];
    const float* bz = (const float*)d_in[15];

    ushort* whi = (ushort*)d_ws;                  // 256 KB
    ushort* wlo = whi + 4 * 128 * 256;            // 256 KB

    prep_weights<<<512, 256, 0, stream>>>(Wi, Ui, Wf, Uf, Wo, Uo, Wz, Uz, whi, wlo);
    slstm_main<<<GRID, 512, 0, stream>>>(x, h, cp, np, bi, bf, bo, bz, whi, wlo,
                                         (float*)d_out);
}

// Round 4
// 394.209 us; speedup vs baseline: 1.9860x; 1.9860x over previous
//
#include <hip/hip_runtime.h>
#include <hip/hip_bf16.h>

typedef __attribute__((ext_vector_type(8))) short bf16x8;
typedef __attribute__((ext_vector_type(4))) float f32x4;

#define NROWS 262144
#define MBLK  64
#define NBLKS (NROWS / MBLK)   /* 4096 */

// ---------------------------------------------------------------------------
// Weight prep: MFMA B-fragment-layout bf16 hi/lo copies,
// Wbig[gate][n=0..127][k=0..255] (k<128 -> W, else U).
// ---------------------------------------------------------------------------
__global__ void prep_weights(
    const float* __restrict__ Wi, const float* __restrict__ Ui,
    const float* __restrict__ Wf, const float* __restrict__ Uf,
    const float* __restrict__ Wo, const float* __restrict__ Uo,
    const float* __restrict__ Wz, const float* __restrict__ Uz,
    ushort* __restrict__ hi, ushort* __restrict__ lo)
{
    int idx = blockIdx.x * 256 + threadIdx.x;   // 0..131071
    int j    = idx & 7;
    int lane = (idx >> 3) & 63;
    int kk   = (idx >> 9) & 7;
    int ni   = (idx >> 12) & 7;
    int g    = idx >> 15;
    int n = ni * 16 + (lane & 15);
    int k = kk * 32 + (lane >> 4) * 8 + j;
    const float* W; const float* U;
    if (g == 0)      { W = Wi; U = Ui; }
    else if (g == 1) { W = Wf; U = Uf; }
    else if (g == 2) { W = Wo; U = Uo; }
    else             { W = Wz; U = Uz; }
    float w = (k < 128) ? W[n * 128 + k] : U[n * 128 + (k - 128)];
    __hip_bfloat16 hb = __float2bfloat16(w);
    float r = w - __bfloat162float(hb);
    __hip_bfloat16 lb = __float2bfloat16(r);
    hi[idx] = *reinterpret_cast<ushort*>(&hb);
    lo[idx] = *reinterpret_cast<ushort*>(&lb);
}

// ---------------------------------------------------------------------------
// Main fused kernel. 4096 blocks x 1 tile; block = 512 thr = 8 waves.
// launch_bounds(512,4): cap total regs at 128 -> 2 blocks/CU (TLP hides
// phase latency). x/h/c/n loads and out stores are nontemporal so the
// streamed 896 MB doesn't evict the L2-resident 512 KB weight fragments.
// ---------------------------------------------------------------------------
__global__ __launch_bounds__(512, 4) void slstm_main(
    const float* __restrict__ x,     const float* __restrict__ hprev,
    const float* __restrict__ cprev, const float* __restrict__ nprev,
    const float* __restrict__ bi,    const float* __restrict__ bfg,
    const float* __restrict__ bo,    const float* __restrict__ bz,
    const ushort* __restrict__ whi,  const ushort* __restrict__ wlo,
    float* __restrict__ out)
{
    __shared__ ushort Ahi[64 * 256];   // 32 KB, swizzled bf16-hi of [x|h]
    __shared__ ushort Alo[64 * 256];   // 32 KB, swizzled bf16-lo
    float* pre = reinterpret_cast<float*>(Ahi);   // epilogue alias
    char* AhiB = reinterpret_cast<char*>(Ahi);
    char* AloB = reinterpret_cast<char*>(Alo);

    const int tid  = threadIdx.x;
    const int row0 = blockIdx.x * MBLK;

    // ---- stage A: nontemporal fp32 loads, split to bf16 hi+lo, swizzled LDS
    #pragma unroll
    for (int i = 0; i < 4; ++i) {
        int f4  = tid + i * 512;
        int row = f4 >> 5;
        int c4  = f4 & 31;
        const f32x4* px = reinterpret_cast<const f32x4*>(x) + (size_t)(row0 + row) * 32 + c4;
        const f32x4* ph = reinterpret_cast<const f32x4*>(hprev) + (size_t)(row0 + row) * 32 + c4;
        f32x4 vx = __builtin_nontemporal_load(px);
        f32x4 vh = __builtin_nontemporal_load(ph);
        #pragma unroll
        for (int half = 0; half < 2; ++half) {
            f32x4 v = half ? vh : vx;
            int kbase = half * 128 + 4 * c4;
            int q   = kbase >> 3;
            int sub = (kbase & 7) * 2;
            int byt = row * 512 + ((q ^ (row & 7)) << 4) + sub;
            ushort h4[4], l4v[4];
            #pragma unroll
            for (int e = 0; e < 4; ++e) {
                float ve = v[e];
                __hip_bfloat16 hb = __float2bfloat16(ve);
                float r = ve - __bfloat162float(hb);
                __hip_bfloat16 lb = __float2bfloat16(r);
                h4[e]  = *reinterpret_cast<ushort*>(&hb);
                l4v[e] = *reinterpret_cast<ushort*>(&lb);
            }
            uint2 hp, lp;
            hp.x = (uint)h4[0] | ((uint)h4[1] << 16);
            hp.y = (uint)h4[2] | ((uint)h4[3] << 16);
            lp.x = (uint)l4v[0] | ((uint)l4v[1] << 16);
            lp.y = (uint)l4v[2] | ((uint)l4v[3] << 16);
            *reinterpret_cast<uint2*>(AhiB + byt) = hp;
            *reinterpret_cast<uint2*>(AloB + byt) = lp;
        }
    }
    __syncthreads();

    // ---- K-loop: 3-term split-precision MFMA ----
    const int wid  = tid >> 6;
    const int lane = tid & 63;
    const int g    = wid & 3;
    const int ch   = wid >> 2;
    const int l15  = lane & 15;
    const int lg   = lane >> 4;

    // wave-constant B base: element off = (g*64+ch*32)*512 + lane*8 + (ni*8+kk)*512
    const ushort* whiW = whi + (size_t)(g * 64 + ch * 32) * 512 + lane * 8;
    const ushort* wloW = wlo + (size_t)(g * 64 + ch * 32) * 512 + lane * 8;

    f32x4 acc[4][4] = {};   // [mi][ni] ; wave tile = 64 rows x 64 cols

    #pragma unroll
    for (int kk = 0; kk < 8; ++kk) {
        bf16x8 ah[4], al[4];
        #pragma unroll
        for (int mi = 0; mi < 4; ++mi) {
            int row = mi * 16 + l15;
            int q   = kk * 4 + lg;
            int byt = row * 512 + ((q ^ (row & 7)) << 4);
            ah[mi] = *reinterpret_cast<const bf16x8*>(AhiB + byt);
            al[mi] = *reinterpret_cast<const bf16x8*>(AloB + byt);
        }
        #pragma unroll
        for (int ni = 0; ni < 4; ++ni) {
            int eoff = (ni * 8 + kk) * 512;
            bf16x8 bh = *reinterpret_cast<const bf16x8*>(whiW + eoff);
            bf16x8 bl = *reinterpret_cast<const bf16x8*>(wloW + eoff);
            #pragma unroll
            for (int mi = 0; mi < 4; ++mi)
                acc[mi][ni] = __builtin_amdgcn_mfma_f32_16x16x32_bf16(ah[mi], bh, acc[mi][ni], 0, 0, 0);
            #pragma unroll
            for (int mi = 0; mi < 4; ++mi)
                acc[mi][ni] = __builtin_amdgcn_mfma_f32_16x16x32_bf16(ah[mi], bl, acc[mi][ni], 0, 0, 0);
            #pragma unroll
            for (int mi = 0; mi < 4; ++mi)
                acc[mi][ni] = __builtin_amdgcn_mfma_f32_16x16x32_bf16(al[mi], bh, acc[mi][ni], 0, 0, 0);
        }
    }

    // ---- epilogue: 4 chunks of 16 rows; swizzled pre; JIT nt c/n loads ----
    const size_t OUTS = (size_t)NROWS * 128;
    const int c  = tid & 127;
    const int r0 = tid >> 7;
    const float bic = bi[c], bfc = bfg[c], boc = bo[c], bzc = bz[c];

    #pragma unroll
    for (int mi = 0; mi < 4; ++mi) {
        __syncthreads();   // K-loop LDS reads / prev chunk reads complete
        #pragma unroll
        for (int ni = 0; ni < 4; ++ni) {
            int colF = g * 128 + ch * 64 + ni * 16 + l15;
            #pragma unroll
            for (int r = 0; r < 4; ++r) {
                int rowp = lg * 4 + r;
                pre[rowp * 512 + (colF ^ ((rowp & 4) << 2))] = acc[mi][ni][r];
            }
        }
        __syncthreads();

        #pragma unroll
        for (int it = 0; it < 4; ++it) {
            int r = r0 + it * 4;
            int sw = (r & 4) << 2;
            size_t gidx = (size_t)(row0 + mi * 16 + r) * 128 + c;
            float cpv = __builtin_nontemporal_load(cprev + gidx);
            float npv = __builtin_nontemporal_load(nprev + gidx);
            float pit = pre[r * 512 + ((      c) ^ sw)] + bic;
            float pft = pre[r * 512 + ((128 + c) ^ sw)] + bfc;
            float pot = pre[r * 512 + ((256 + c) ^ sw)] + boc;
            float pzt = pre[r * 512 + ((384 + c) ^ sw)] + bzc;
            float m   = fmaxf(pft, pit);
            float i_t = __expf(pit - m);
            float f_t = __builtin_amdgcn_rcpf(1.0f + __expf(-pft)) + __expf(pft - m);
            float o_t = __builtin_amdgcn_rcpf(1.0f + __expf(-pot));
            float zc  = fminf(fmaxf(pzt, -15.0f), 15.0f);
            float e2  = __expf(2.0f * zc);
            float z_t = (e2 - 1.0f) * __builtin_amdgcn_rcpf(e2 + 1.0f);
            float c_t = f_t * cpv + i_t * z_t;
            float n_t = f_t * npv + i_t;
            float h_t = o_t * c_t * __builtin_amdgcn_rcpf(n_t + 1e-8f);
            __builtin_nontemporal_store(h_t, out + gidx);
            __builtin_nontemporal_store(c_t, out + OUTS + gidx);
            __builtin_nontemporal_store(n_t, out + 2 * OUTS + gidx);
        }
    }
}

extern "C" void kernel_launch(void* const* d_in, const int* in_sizes, int n_in,
                              void* d_out, int out_size, void* d_ws, size_t ws_size,
                              hipStream_t stream) {
    const float* x  = (const float*)d_in[0];
    const float* h  = (const float*)d_in[1];
    const float* cp = (const float*)d_in[2];
    const float* np = (const float*)d_in[3];
    const float* Wi = (const float*)d_in[4];
    const float* Ui = (const float*)d_in[5];
    const float* Wf = (const float*)d_in[6];
    const float* Uf = (const float*)d_in[7];
    const float* Wo = (const float*)d_in[8];
    const float* Uo = (const float*)d_in[9];
    const float* Wz = (const float*)d_in[10];
    const float* Uz = (const float*)d_in[11];
    const float* bi = (const float*)d_in[12];
    const float* bf = (const float*)d_in[13];
    const float* bo = (const float*)d_in[14];
    const float* bz = (const float*)d_in[15];

    ushort* whi = (ushort*)d_ws;                  // 256 KB
    ushort* wlo = whi + 4 * 128 * 256;            // 256 KB

    prep_weights<<<512, 256, 0, stream>>>(Wi, Ui, Wf, Uf, Wo, Uo, Wz, Uz, whi, wlo);
    slstm_main<<<NBLKS, 512, 0, stream>>>(x, h, cp, np, bi, bf, bo, bz, whi, wlo,
                                          (float*)d_out);
}

// Round 5
// 330.963 us; speedup vs baseline: 2.3656x; 1.1911x over previous
//
#include <hip/hip_runtime.h>
#include <hip/hip_bf16.h>

typedef __attribute__((ext_vector_type(8))) short bf16x8;
typedef __attribute__((ext_vector_type(4))) float f32x4;

#define NROWS 262144
#define MBLK  64
#define NBLKS (NROWS / MBLK)   /* 4096 */

// ---------------------------------------------------------------------------
// Weight prep: MFMA B-fragment-layout bf16 hi/lo copies,
// Wbig[gate][n=0..127][k=0..255] (k<128 -> W, else U).
// ---------------------------------------------------------------------------
__global__ void prep_weights(
    const float* __restrict__ Wi, const float* __restrict__ Ui,
    const float* __restrict__ Wf, const float* __restrict__ Uf,
    const float* __restrict__ Wo, const float* __restrict__ Uo,
    const float* __restrict__ Wz, const float* __restrict__ Uz,
    ushort* __restrict__ hi, ushort* __restrict__ lo)
{
    int idx = blockIdx.x * 256 + threadIdx.x;   // 0..131071
    int j    = idx & 7;
    int lane = (idx >> 3) & 63;
    int kk   = (idx >> 9) & 7;
    int ni   = (idx >> 12) & 7;
    int g    = idx >> 15;
    int n = ni * 16 + (lane & 15);
    int k = kk * 32 + (lane >> 4) * 8 + j;
    const float* W; const float* U;
    if (g == 0)      { W = Wi; U = Ui; }
    else if (g == 1) { W = Wf; U = Uf; }
    else if (g == 2) { W = Wo; U = Uo; }
    else             { W = Wz; U = Uz; }
    float w = (k < 128) ? W[n * 128 + k] : U[n * 128 + (k - 128)];
    __hip_bfloat16 hb = __float2bfloat16(w);
    float r = w - __bfloat162float(hb);
    __hip_bfloat16 lb = __float2bfloat16(r);
    hi[idx] = *reinterpret_cast<ushort*>(&hb);
    lo[idx] = *reinterpret_cast<ushort*>(&lb);
}

// ---------------------------------------------------------------------------
// Main fused kernel. 4096 blocks x 1 tile; block = 512 thr = 8 waves.
// 128 KB LDS: bytes [0,64K) = swizzled bf16 hi/lo A-tile for the K-loop;
// whole 128 KB reused as pre[64][512] fp32 for a SINGLE-chunk epilogue
// (3 barriers per block instead of 9; one c/n latency window, hoisted
// under the K-loop's MFMAs).
// ---------------------------------------------------------------------------
__global__ __launch_bounds__(512, 2) void slstm_main(
    const float* __restrict__ x,     const float* __restrict__ hprev,
    const float* __restrict__ cprev, const float* __restrict__ nprev,
    const float* __restrict__ bi,    const float* __restrict__ bfg,
    const float* __restrict__ bo,    const float* __restrict__ bz,
    const ushort* __restrict__ whi,  const ushort* __restrict__ wlo,
    float* __restrict__ out)
{
    __shared__ float pre[64 * 512];               // 128 KB
    char*   AhiB = reinterpret_cast<char*>(pre);  // first 32 KB: bf16-hi A
    char*   AloB = AhiB + 64 * 256 * 2;           // next 32 KB: bf16-lo A

    const int tid  = threadIdx.x;
    const int row0 = blockIdx.x * MBLK;

    // ---- stage A: fp32 loads, split to bf16 hi+lo, swizzled LDS ----
    #pragma unroll
    for (int i = 0; i < 4; ++i) {
        int f4  = tid + i * 512;
        int row = f4 >> 5;
        int c4  = f4 & 31;
        f32x4 vx = reinterpret_cast<const f32x4*>(x)[(size_t)(row0 + row) * 32 + c4];
        f32x4 vh = reinterpret_cast<const f32x4*>(hprev)[(size_t)(row0 + row) * 32 + c4];
        #pragma unroll
        for (int half = 0; half < 2; ++half) {
            f32x4 v = half ? vh : vx;
            int kbase = half * 128 + 4 * c4;
            int q   = kbase >> 3;
            int sub = (kbase & 7) * 2;
            int byt = row * 512 + ((q ^ (row & 7)) << 4) + sub;
            ushort h4[4], l4v[4];
            #pragma unroll
            for (int e = 0; e < 4; ++e) {
                float ve = v[e];
                __hip_bfloat16 hb = __float2bfloat16(ve);
                float r = ve - __bfloat162float(hb);
                __hip_bfloat16 lb = __float2bfloat16(r);
                h4[e]  = *reinterpret_cast<ushort*>(&hb);
                l4v[e] = *reinterpret_cast<ushort*>(&lb);
            }
            uint2 hp, lp;
            hp.x = (uint)h4[0] | ((uint)h4[1] << 16);
            hp.y = (uint)h4[2] | ((uint)h4[3] << 16);
            lp.x = (uint)l4v[0] | ((uint)l4v[1] << 16);
            lp.y = (uint)l4v[2] | ((uint)l4v[3] << 16);
            *reinterpret_cast<uint2*>(AhiB + byt) = hp;
            *reinterpret_cast<uint2*>(AloB + byt) = lp;
        }
    }
    __syncthreads();   // bar 1

    const int wid  = tid >> 6;
    const int lane = tid & 63;
    const int g    = wid & 3;
    const int ch   = wid >> 2;
    const int l15  = lane & 15;
    const int lg   = lane >> 4;
    const int c    = tid & 127;        // epilogue column (within gate)
    const int r0   = tid >> 7;         // epilogue row phase 0..3

    // ---- hoist c/n loads: latency hides under the K-loop ----
    float cpr[16], npr[16];
    #pragma unroll
    for (int it = 0; it < 16; ++it) {
        int rr = r0 + it * 4;
        size_t gidx = (size_t)(row0 + rr) * 128 + c;
        cpr[it] = cprev[gidx];
        npr[it] = nprev[gidx];
    }

    // wave-constant B base
    const ushort* whiW = whi + (size_t)(g * 64 + ch * 32) * 512 + lane * 8;
    const ushort* wloW = wlo + (size_t)(g * 64 + ch * 32) * 512 + lane * 8;

    // ---- K-loop: 3-term split-precision MFMA ----
    f32x4 acc[4][4] = {};   // [mi][ni]; wave tile = 64 rows x 64 cols

    #pragma unroll
    for (int kk = 0; kk < 8; ++kk) {
        bf16x8 ah[4], al[4];
        #pragma unroll
        for (int mi = 0; mi < 4; ++mi) {
            int row = mi * 16 + l15;
            int q   = kk * 4 + lg;
            int byt = row * 512 + ((q ^ (row & 7)) << 4);
            ah[mi] = *reinterpret_cast<const bf16x8*>(AhiB + byt);
            al[mi] = *reinterpret_cast<const bf16x8*>(AloB + byt);
        }
        #pragma unroll
        for (int ni = 0; ni < 4; ++ni) {
            int eoff = (ni * 8 + kk) * 512;
            bf16x8 bh = *reinterpret_cast<const bf16x8*>(whiW + eoff);
            bf16x8 bl = *reinterpret_cast<const bf16x8*>(wloW + eoff);
            #pragma unroll
            for (int mi = 0; mi < 4; ++mi)
                acc[mi][ni] = __builtin_amdgcn_mfma_f32_16x16x32_bf16(ah[mi], bh, acc[mi][ni], 0, 0, 0);
            #pragma unroll
            for (int mi = 0; mi < 4; ++mi)
                acc[mi][ni] = __builtin_amdgcn_mfma_f32_16x16x32_bf16(ah[mi], bl, acc[mi][ni], 0, 0, 0);
            #pragma unroll
            for (int mi = 0; mi < 4; ++mi)
                acc[mi][ni] = __builtin_amdgcn_mfma_f32_16x16x32_bf16(al[mi], bh, acc[mi][ni], 0, 0, 0);
        }
    }
    __syncthreads();   // bar 2: all A-LDS reads done; safe to overwrite as pre

    // ---- single-chunk epilogue: all 64 rows at once ----
    #pragma unroll
    for (int mi = 0; mi < 4; ++mi)
        #pragma unroll
        for (int ni = 0; ni < 4; ++ni) {
            int colF = g * 128 + ch * 64 + ni * 16 + l15;
            #pragma unroll
            for (int r = 0; r < 4; ++r) {
                int rowp = mi * 16 + lg * 4 + r;
                pre[rowp * 512 + (colF ^ ((rowp & 4) << 2))] = acc[mi][ni][r];
            }
        }
    __syncthreads();   // bar 3

    const size_t OUTS = (size_t)NROWS * 128;
    const float bic = bi[c], bfc = bfg[c], boc = bo[c], bzc = bz[c];

    #pragma unroll
    for (int it = 0; it < 16; ++it) {
        int rr = r0 + it * 4;
        int sw = (rr & 4) << 2;
        size_t gidx = (size_t)(row0 + rr) * 128 + c;
        float pit = pre[rr * 512 + ((      c) ^ sw)] + bic;
        float pft = pre[rr * 512 + ((128 + c) ^ sw)] + bfc;
        float pot = pre[rr * 512 + ((256 + c) ^ sw)] + boc;
        float pzt = pre[rr * 512 + ((384 + c) ^ sw)] + bzc;
        float m   = fmaxf(pft, pit);
        float i_t = __expf(pit - m);
        float f_t = __builtin_amdgcn_rcpf(1.0f + __expf(-pft)) + __expf(pft - m);
        float o_t = __builtin_amdgcn_rcpf(1.0f + __expf(-pot));
        float zc  = fminf(fmaxf(pzt, -15.0f), 15.0f);
        float e2  = __expf(2.0f * zc);
        float z_t = (e2 - 1.0f) * __builtin_amdgcn_rcpf(e2 + 1.0f);
        float c_t = f_t * cpr[it] + i_t * z_t;
        float n_t = f_t * npr[it] + i_t;
        float h_t = o_t * c_t * __builtin_amdgcn_rcpf(n_t + 1e-8f);
        out[gidx]            = h_t;
        out[OUTS + gidx]     = c_t;
        out[2 * OUTS + gidx] = n_t;
    }
}

extern "C" void kernel_launch(void* const* d_in, const int* in_sizes, int n_in,
                              void* d_out, int out_size, void* d_ws, size_t ws_size,
                              hipStream_t stream) {
    const float* x  = (const float*)d_in[0];
    const float* h  = (const float*)d_in[1];
    const float* cp = (const float*)d_in[2];
    const float* np = (const float*)d_in[3];
    const float* Wi = (const float*)d_in[4];
    const float* Ui = (const float*)d_in[5];
    const float* Wf = (const float*)d_in[6];
    const float* Uf = (const float*)d_in[7];
    const float* Wo = (const float*)d_in[8];
    const float* Uo = (const float*)d_in[9];
    const float* Wz = (const float*)d_in[10];
    const float* Uz = (const float*)d_in[11];
    const float* bi = (const float*)d_in[12];
    const float* bf = (const float*)d_in[13];
    const float* bo = (const float*)d_in[14];
    const float* bz = (const float*)d_in[15];

    ushort* whi = (ushort*)d_ws;                  // 256 KB
    ushort* wlo = whi + 4 * 128 * 256;            // 256 KB

    prep_weights<<<512, 256, 0, stream>>>(Wi, Ui, Wf, Uf, Wo, Uo, Wz, Uz, whi, wlo);
    slstm_main<<<NBLKS, 512, 0, stream>>>(x, h, cp, np, bi, bf, bo, bz, whi, wlo,
                                          (float*)d_out);
}